// Round 7
// baseline (388.775 us; speedup 1.0000x reference)
//
#include <hip/hip_runtime.h>
#include <hip/hip_bf16.h>

#define N_NODES 50000
#define N_EDGES 1600000
#define DIM 128
#define N_LAYERS 3
#define N_GRAPHS 128

#define NBUCK 196          // ceil(50000/256) buckets of 256 nodes
#define T1 4096            // edges per partition block
#define G1 ((N_EDGES + T1 - 1) / T1)   // 391

#define NCHUNK 4           // feature chunks of 32 (64B per row-chunk)
#define NWAVE_N 12500      // node-waves per chunk (50000/4 per block)

typedef __attribute__((ext_vector_type(8))) short bf16x8;
typedef __attribute__((ext_vector_type(4))) float f32x4;

// ------------------------------------------------------------ bf16 helpers
__device__ __forceinline__ float bfu2f(unsigned short u) {
    union { unsigned int i; float f; } c; c.i = ((unsigned int)u) << 16; return c.f;
}
__device__ __forceinline__ unsigned short f2bfu(float f) {
    __hip_bfloat16 h = __float2bfloat16(f);  // RNE
    return *reinterpret_cast<unsigned short*>(&h);
}

// ---------------------------------------------------------------- utilities
__global__ void zero_counts_kernel(int* __restrict__ bc) {
    if (threadIdx.x < 256) bc[threadIdx.x] = 0;
}

__global__ __launch_bounds__(256) void cvt_kernel(const float4* __restrict__ x,
                                                  ushort4* __restrict__ xb, int n4) {
    int i = blockIdx.x * blockDim.x + threadIdx.x;
    if (i < n4) {
        float4 v = x[i];
        ushort4 o;
        o.x = f2bfu(v.x); o.y = f2bfu(v.y); o.z = f2bfu(v.z); o.w = f2bfu(v.w);
        xb[i] = o;
    }
}

// Pack W into MFMA-fragment-major bf16 (layout verified round 5):
// t = (((layer*2+mat)*4+kt)*8+ct)*64+lane ; elem j -> W[k=kt*32+(lane>>4)*8+j][n=ct*16+(lane&15)]
__global__ __launch_bounds__(256) void pack_w_kernel(const float* __restrict__ Wl,
                                                     const float* __restrict__ Wr,
                                                     unsigned short* __restrict__ wp) {
    int t = blockIdx.x * blockDim.x + threadIdx.x;
    if (t >= 3 * 2 * 4 * 8 * 64) return;
    int lane = t & 63;
    int rest = t >> 6;
    int ct = rest & 7; rest >>= 3;
    int kt = rest & 3; rest >>= 2;
    int mat = rest & 1; rest >>= 1;
    int layer = rest;
    const float* W = (mat ? Wr : Wl) + (size_t)layer * DIM * DIM;
    int col = ct * 16 + (lane & 15);
    int k0 = kt * 32 + (lane >> 4) * 8;
    unsigned short* dst = wp + (size_t)t * 8;
#pragma unroll
    for (int j = 0; j < 8; j++) dst[j] = f2bfu(W[(k0 + j) * DIM + col]);
}

// --------------------------------------------------- CSR build, bucket-sorted
__global__ __launch_bounds__(256) void pass0_bcount(const int* __restrict__ ei,
                                                    int* __restrict__ bcount) {
    __shared__ int h[256];
    int tid = threadIdx.x;
    h[tid] = 0;
    __syncthreads();
    int e0 = blockIdx.x * T1;
    int e1 = min(e0 + T1, N_EDGES);
    for (int e = e0 + tid; e < e1; e += 256) atomicAdd(&h[ei[N_EDGES + e] >> 8], 1);
    __syncthreads();
    if (h[tid]) atomicAdd(&bcount[tid], h[tid]);
}

__global__ __launch_bounds__(256) void scan196_kernel(const int* __restrict__ bcount,
                                                      int* __restrict__ bbase,
                                                      int* __restrict__ cursor) {
    __shared__ int sc[256];
    int tid = threadIdx.x;
    int v = (tid < NBUCK) ? bcount[tid] : 0;
    sc[tid] = v;
    __syncthreads();
    for (int off = 1; off < 256; off <<= 1) {
        int t = (tid >= off) ? sc[tid - off] : 0;
        __syncthreads();
        sc[tid] += t;
        __syncthreads();
    }
    int excl = sc[tid] - v;
    if (tid <= NBUCK) {
        bbase[tid] = excl;
        cursor[tid] = excl;
    }
    if (tid == NBUCK - 1) bbase[NBUCK] = sc[tid];
}

__global__ __launch_bounds__(256) void pass1_partition(const int* __restrict__ ei,
                                                       int* __restrict__ cursor,
                                                       int2* __restrict__ pairs) {
    __shared__ int h[256], sc[256], o[256], c[256], gb[256];
    __shared__ int2 stg[T1];
    int tid = threadIdx.x;
    int e0 = blockIdx.x * T1;
    int e1 = min(e0 + T1, N_EDGES);
    h[tid] = 0;
    __syncthreads();
    for (int e = e0 + tid; e < e1; e += 256) atomicAdd(&h[ei[N_EDGES + e] >> 8], 1);
    __syncthreads();
    int myc = h[tid];
    sc[tid] = myc;
    __syncthreads();
    for (int off = 1; off < 256; off <<= 1) {
        int t = (tid >= off) ? sc[tid - off] : 0;
        __syncthreads();
        sc[tid] += t;
        __syncthreads();
    }
    o[tid] = sc[tid] - myc;
    c[tid] = o[tid];
    __syncthreads();
    for (int e = e0 + tid; e < e1; e += 256) {
        int s = ei[e];
        int d = ei[N_EDGES + e];
        int p = atomicAdd(&c[d >> 8], 1);
        stg[p] = make_int2(s, d);
    }
    __syncthreads();
    if (tid < NBUCK && myc) gb[tid] = atomicAdd(&cursor[tid], myc);
    __syncthreads();
    int cnt = e1 - e0;
    for (int j = tid; j < cnt; j += 256) {
        int2 pr = stg[j];
        int bk = pr.y >> 8;
        pairs[gb[bk] + (j - o[bk])] = pr;
    }
}

// pass2: one block per bucket; csr stored as USHORT (node ids < 65536)
__global__ __launch_bounds__(256) void pass2_fill(const int2* __restrict__ pairs,
                                                  const int* __restrict__ bbase,
                                                  int* __restrict__ row_ptr,
                                                  float* __restrict__ inv_deg,
                                                  unsigned short* __restrict__ csr16) {
    __shared__ int lh[256], sc[256], lf[256];
    int tid = threadIdx.x;
    int b = blockIdx.x;
    int n0 = b << 8;
    int p0 = bbase[b], p1 = bbase[b + 1];
    lh[tid] = 0;
    __syncthreads();
    for (int p = p0 + tid; p < p1; p += 256) atomicAdd(&lh[pairs[p].y & 255], 1);
    __syncthreads();
    int deg = lh[tid];
    sc[tid] = deg;
    __syncthreads();
    for (int off = 1; off < 256; off <<= 1) {
        int t = (tid >= off) ? sc[tid - off] : 0;
        __syncthreads();
        sc[tid] += t;
        __syncthreads();
    }
    int base = p0 + sc[tid] - deg;
    int node = n0 + tid;
    if (node < N_NODES) {
        row_ptr[node] = base;
        inv_deg[node] = (deg > 0) ? 1.0f / (float)deg : 0.0f;
    }
    if (b == NBUCK - 1 && tid == 0) row_ptr[N_NODES] = p1;
    lf[tid] = base;
    __syncthreads();
    for (int p = p0 + tid; p < p1; p += 256) {
        int2 pr = pairs[p];
        int pos = atomicAdd(&lf[pr.y & 255], 1);
        csr16[pos] = (unsigned short)pr.x;
    }
}

// ------------------------------------------------------------- aggregation
// Feature-chunked gather: chunk = 32 features = 64B per row (one line).
// Per-chunk working set = 3.2MB -> per-XCD-L2 resident. Chunk-major block
// order keeps chunks time-separated. Wave = one (node, chunk): 16 edge-slots
// x 4 lanes x int4; shfl_xor(4/8/16/32) tree; lanes 0-3 write 64B.
__device__ __forceinline__ void acc8(int4 v, float* a) {
    union { int i; float f; } t;
    t.i = v.x << 16;         a[0] += t.f;
    t.i = v.x & 0xffff0000;  a[1] += t.f;
    t.i = v.y << 16;         a[2] += t.f;
    t.i = v.y & 0xffff0000;  a[3] += t.f;
    t.i = v.z << 16;         a[4] += t.f;
    t.i = v.z & 0xffff0000;  a[5] += t.f;
    t.i = v.w << 16;         a[6] += t.f;
    t.i = v.w & 0xffff0000;  a[7] += t.f;
}

__global__ __launch_bounds__(256) void agg_kernel(const unsigned short* __restrict__ xb,
                                                  const unsigned short* __restrict__ csr16,
                                                  const int* __restrict__ row_ptr,
                                                  const float* __restrict__ inv_deg,
                                                  unsigned short* __restrict__ aggb) {
    const int chunk = blockIdx.x / NWAVE_N;                    // 0..3
    const int nw    = blockIdx.x % NWAVE_N;
    const int node  = nw * 4 + (threadIdx.x >> 6);
    const int lane  = threadIdx.x & 63;
    const int grp   = lane >> 2;   // 0..15 edge slot
    const int sub   = lane & 3;    // 16B piece of the 64B chunk
    const unsigned short* xc = xb + chunk * 32;                 // chunk column base

    int e0 = row_ptr[node], e1 = row_ptr[node + 1];
    float a[8] = {0.f, 0.f, 0.f, 0.f, 0.f, 0.f, 0.f, 0.f};
    int e = e0;
    for (; e + 32 <= e1; e += 32) {
        int ia = csr16[e + grp];
        int ib = csr16[e + 16 + grp];
        int4 va = *(const int4*)(xc + (size_t)ia * DIM + sub * 8);
        int4 vb = *(const int4*)(xc + (size_t)ib * DIM + sub * 8);
        acc8(va, a);
        acc8(vb, a);
    }
    if (e + 16 <= e1) {
        int ia = csr16[e + grp];
        int4 va = *(const int4*)(xc + (size_t)ia * DIM + sub * 8);
        acc8(va, a);
        e += 16;
    }
    if (e + grp < e1) {
        int ia = csr16[e + grp];
        int4 va = *(const int4*)(xc + (size_t)ia * DIM + sub * 8);
        acc8(va, a);
    }
#pragma unroll
    for (int k = 0; k < 8; k++) {
        a[k] += __shfl_xor(a[k], 4);
        a[k] += __shfl_xor(a[k], 8);
        a[k] += __shfl_xor(a[k], 16);
        a[k] += __shfl_xor(a[k], 32);
    }
    if (grp == 0) {
        float w = inv_deg[node];
        int4 o;
        o.x = ((int)f2bfu(a[1] * w) << 16) | f2bfu(a[0] * w);
        o.y = ((int)f2bfu(a[3] * w) << 16) | f2bfu(a[2] * w);
        o.z = ((int)f2bfu(a[5] * w) << 16) | f2bfu(a[4] * w);
        o.w = ((int)f2bfu(a[7] * w) << 16) | f2bfu(a[6] * w);
        *(int4*)(aggb + (size_t)node * DIM + chunk * 32 + sub * 8) = o;
    }
}

// ---------------------------------------------------------------- MFMA GEMM
// out = [agg | x] @ [Wl ; Wr] + bias (+ReLU). Layout verified round 5.
template <int OUT_BF16, int RELU>
__global__ __launch_bounds__(256) void gemm_mfma_kernel(
    const unsigned short* __restrict__ aggb,
    const unsigned short* __restrict__ xb,
    const unsigned short* __restrict__ wp,
    const float* __restrict__ bias,
    unsigned short* __restrict__ outb,
    float* __restrict__ outf) {
    const int NT = N_NODES / 16;  // 3125
    int wid = (blockIdx.x * blockDim.x + threadIdx.x) >> 6;
    int lane = threadIdx.x & 63;
    int ch  = wid & 1;
    int rt0 = (wid >> 1) * 2;
    if (rt0 >= NT) return;
    const bool has1 = (rt0 + 1) < NT;
    const int R0 = rt0 * 16, R1 = R0 + 16;
    const int l15 = lane & 15, l4 = lane >> 4;

    f32x4 acc[2][4];
#pragma unroll
    for (int c = 0; c < 4; c++) {
        float bv = bias[(ch * 4 + c) * 16 + l15];
        acc[0][c] = (f32x4){bv, bv, bv, bv};
        acc[1][c] = acc[0][c];
    }

#pragma unroll
    for (int mat = 0; mat < 2; mat++) {
        const unsigned short* src = mat ? xb : aggb;
        const unsigned short* wbase = wp + mat * (4 * 8 * 64 * 8);
#pragma unroll
        for (int kt = 0; kt < 4; kt++) {
            bf16x8 a0 = *(const bf16x8*)(src + (size_t)(R0 + l15) * DIM + kt * 32 + l4 * 8);
            bf16x8 a1 = {};
            if (has1) a1 = *(const bf16x8*)(src + (size_t)(R1 + l15) * DIM + kt * 32 + l4 * 8);
            const unsigned short* wk = wbase + kt * (8 * 64 * 8) + lane * 8;
#pragma unroll
            for (int c = 0; c < 4; c++) {
                bf16x8 bf = *(const bf16x8*)(wk + (ch * 4 + c) * (64 * 8));
                acc[0][c] = __builtin_amdgcn_mfma_f32_16x16x32_bf16(a0, bf, acc[0][c], 0, 0, 0);
                if (has1)
                    acc[1][c] = __builtin_amdgcn_mfma_f32_16x16x32_bf16(a1, bf, acc[1][c], 0, 0, 0);
            }
        }
    }

#pragma unroll
    for (int m = 0; m < 2; m++) {
        if (m && !has1) break;
        int r0 = (m ? R1 : R0) + l4 * 4;
#pragma unroll
        for (int c = 0; c < 4; c++) {
            int col = (ch * 4 + c) * 16 + l15;
#pragma unroll
            for (int j = 0; j < 4; j++) {
                float v = acc[m][c][j];
                if (RELU) v = fmaxf(v, 0.f);
                if (OUT_BF16) outb[(size_t)(r0 + j) * DIM + col] = f2bfu(v);
                else          outf[(size_t)(r0 + j) * DIM + col] = v;
            }
        }
    }
}

// ------------------------------------------------------------------- pool
__global__ __launch_bounds__(1024) void pool_kernel(const float* __restrict__ xf,
                                                    const int* __restrict__ batch,
                                                    float* __restrict__ out) {
    __shared__ float red[8][DIM];
    int g = blockIdx.x;
    int j = threadIdx.x & 127;
    int rl = threadIdx.x >> 7;
    int lo = 0, hi = N_NODES;
    while (lo < hi) { int m = (lo + hi) >> 1; if (batch[m] < g) lo = m + 1; else hi = m; }
    int start = lo;
    lo = 0; hi = N_NODES;
    while (lo < hi) { int m = (lo + hi) >> 1; if (batch[m] < g + 1) lo = m + 1; else hi = m; }
    int end = lo;
    float acc = 0.f;
    for (int r = start + rl; r < end; r += 8) acc += xf[(size_t)r * DIM + j];
    red[rl][j] = acc;
    __syncthreads();
    if (rl == 0) {
        float s = ((red[0][j] + red[1][j]) + (red[2][j] + red[3][j]))
                + ((red[4][j] + red[5][j]) + (red[6][j] + red[7][j]));
        out[g * DIM + j] = s;
    }
}

// ---------------------------------------------------------------- launcher
extern "C" void kernel_launch(void* const* d_in, const int* in_sizes, int n_in,
                              void* d_out, int out_size, void* d_ws, size_t ws_size,
                              hipStream_t stream) {
    const float* x   = (const float*)d_in[0];
    const int*   ei  = (const int*)d_in[1];
    const int*   bat = (const int*)d_in[2];
    const float* Wl  = (const float*)d_in[3];
    const float* Wr  = (const float*)d_in[4];
    const float* b   = (const float*)d_in[5];
    float* out = (float*)d_out;

    char* ws = (char*)d_ws;
    size_t off = 0;
    auto carve = [&](size_t bytes) {
        void* p = ws + off;
        off += (bytes + 255) & ~(size_t)255;
        return p;
    };
    int*   bcount  = (int*)carve(sizeof(int) * 256);
    int*   bbase   = (int*)carve(sizeof(int) * 256);
    int*   cursor  = (int*)carve(sizeof(int) * 256);
    int*   row_ptr = (int*)carve(sizeof(int) * (N_NODES + 1));
    unsigned short* csr16 = (unsigned short*)carve(sizeof(unsigned short) * N_EDGES);
    float* inv_deg = (float*)carve(sizeof(float) * N_NODES);
    unsigned short* xb    = (unsigned short*)carve(2ull * N_NODES * DIM);
    unsigned short* actA  = (unsigned short*)carve(2ull * N_NODES * DIM);
    unsigned short* actB  = (unsigned short*)carve(2ull * N_NODES * DIM);
    unsigned short* aggb  = (unsigned short*)carve(2ull * N_NODES * DIM);
    unsigned short* wpack = (unsigned short*)carve(2ull * 3 * 2 * 4 * 8 * 64 * 8);
    float* finalf = (float*)carve(sizeof(float) * (size_t)N_NODES * DIM);
    // pairs aliases actB: dead before layer-1 gemm fully rewrites actB
    int2* pairs = (int2*)actB;
    (void)ws_size; (void)in_sizes; (void)n_in; (void)out_size;

    const int n4 = N_NODES * DIM / 4;

    zero_counts_kernel<<<1, 256, 0, stream>>>(bcount);
    cvt_kernel<<<(n4 + 255) / 256, 256, 0, stream>>>((const float4*)x, (ushort4*)xb, n4);
    pack_w_kernel<<<48, 256, 0, stream>>>(Wl, Wr, wpack);
    pass0_bcount<<<G1, 256, 0, stream>>>(ei, bcount);
    scan196_kernel<<<1, 256, 0, stream>>>(bcount, bbase, cursor);
    pass1_partition<<<G1, 256, 0, stream>>>(ei, cursor, pairs);
    pass2_fill<<<NBUCK, 256, 0, stream>>>(pairs, bbase, row_ptr, inv_deg, csr16);

    const int aggGrid  = NCHUNK * NWAVE_N;   // 50000 blocks, chunk-major
    const int gemmGrid = ((N_NODES / 16 + 1) / 2 * 2 * 64 + 255) / 256;
    const size_t wlayer = 2ull * 4 * 8 * 64 * 8;

    // layer 0
    agg_kernel<<<aggGrid, 256, 0, stream>>>(xb, csr16, row_ptr, inv_deg, aggb);
    gemm_mfma_kernel<1, 1><<<gemmGrid, 256, 0, stream>>>(aggb, xb, wpack + 0 * wlayer,
                                                         b + 0 * DIM, actA, nullptr);
    // layer 1
    agg_kernel<<<aggGrid, 256, 0, stream>>>(actA, csr16, row_ptr, inv_deg, aggb);
    gemm_mfma_kernel<1, 1><<<gemmGrid, 256, 0, stream>>>(aggb, actA, wpack + 1 * wlayer,
                                                         b + 1 * DIM, actB, nullptr);
    // layer 2 (f32 out, no relu)
    agg_kernel<<<aggGrid, 256, 0, stream>>>(actB, csr16, row_ptr, inv_deg, aggb);
    gemm_mfma_kernel<0, 0><<<gemmGrid, 256, 0, stream>>>(aggb, actB, wpack + 2 * wlayer,
                                                         b + 2 * DIM, nullptr, finalf);

    pool_kernel<<<N_GRAPHS, 1024, 0, stream>>>(finalf, bat, out);
}